// Round 5
// baseline (242.110 us; speedup 1.0000x reference)
//
#include <hip/hip_runtime.h>

// IF (integrate-and-fire) forward, T=4.
// Per position: mem = 0.5*th; for t: mem += x_t; s = (mem>=th)?th:0; out_t = s; mem -= s.
// R5: software-pipelined persistent waves. R4 post-mortem: VGPR=32 proved the
// compiler serialized loads into 4-in-flight rounds (measured 2.5 TB/s matches
// that model). Here: 1024 blocks, 8 items/thread, 1-ahead prefetch with two
// named register tile sets, so the vmcnt wait for tile k covers loads issued a
// full iteration earlier and waves never churn.

typedef float f32x4 __attribute__((ext_vector_type(4)));

__device__ __forceinline__ f32x4 if_step(f32x4& m, const f32x4 v, const float th) {
    m += v;
    f32x4 s;
    s.x = (m.x >= th) ? th : 0.0f;
    s.y = (m.y >= th) ? th : 0.0f;
    s.z = (m.z >= th) ? th : 0.0f;
    s.w = (m.w >= th) ? th : 0.0f;
    m -= s;
    return s;
}

__global__ __launch_bounds__(256, 4) void if_fwd_kernel(
    const f32x4* __restrict__ x,
    const float* __restrict__ thresh_p,
    f32x4* __restrict__ out,
    int n4,        // f32x4 positions per timestep
    int nthreads)  // total threads = grid stride
{
    const float th = thresh_p[0];
    const float m0 = 0.5f * th;

    int i = blockIdx.x * blockDim.x + threadIdx.x;

    // Prologue: load tile 0 (4 independent loads).
    f32x4 a0 = x[0 * n4 + i];
    f32x4 a1 = x[1 * n4 + i];
    f32x4 a2 = x[2 * n4 + i];
    f32x4 a3 = x[3 * n4 + i];

#pragma unroll
    for (int k = 0; k < 8; ++k) {
        const int inext = i + nthreads;
        f32x4 b0, b1, b2, b3;
        if (k < 7) {
            // Prefetch next tile BEFORE consuming current one; lands while we
            // compute+store below, so the next iteration's wait is short.
            b0 = x[0 * n4 + inext];
            b1 = x[1 * n4 + inext];
            b2 = x[2 * n4 + inext];
            b3 = x[3 * n4 + inext];
        }

        f32x4 m = m0;
        f32x4 s;
        s = if_step(m, a0, th);
        __builtin_nontemporal_store(s, out + 0 * n4 + i);
        s = if_step(m, a1, th);
        __builtin_nontemporal_store(s, out + 1 * n4 + i);
        s = if_step(m, a2, th);
        __builtin_nontemporal_store(s, out + 2 * n4 + i);
        s = if_step(m, a3, th);
        __builtin_nontemporal_store(s, out + 3 * n4 + i);

        a0 = b0; a1 = b1; a2 = b2; a3 = b3;
        i = inext;
    }
}

extern "C" void kernel_launch(void* const* d_in, const int* in_sizes, int n_in,
                              void* d_out, int out_size, void* d_ws, size_t ws_size,
                              hipStream_t stream) {
    const float* x      = (const float*)d_in[0];
    const float* thresh = (const float*)d_in[1];
    float* out          = (float*)d_out;

    const int total   = in_sizes[0];   // 33,554,432 = T*B*C*H*W (T=4)
    const int n_per_t = total / 4;     // 8,388,608
    const int n4      = n_per_t / 4;   // 2,097,152 f32x4 per timestep

    const int block    = 256;
    const int grid     = 1024;                 // 8 items per thread
    const int nthreads = grid * block;         // 262,144

    if_fwd_kernel<<<grid, block, 0, stream>>>(
        (const f32x4*)x, thresh, (f32x4*)out, n4, nthreads);
}

// Round 6
// 230.589 us; speedup vs baseline: 1.0500x; 1.0500x over previous
//
#include <hip/hip_runtime.h>

// IF (integrate-and-fire) forward, T=4.
// Per position: mem = 0.5*th; for t: mem += x_t; s = (mem>=th)?th:0; out_t = s; mem -= s.
// R6: R4's one-shot 2048-block structure, but the 16-load burst is PINNED with
// __builtin_amdgcn_sched_barrier(0) so the compiler cannot sink loads to uses
// (R4/R5 post-mortem: VGPR=28..32 proved it kept sinking; 2.5 TB/s matches the
// resulting ~4KB/CU in-flight). Plain stores (L2 write absorption gives fast
// store acks — the harness fill hits 6.7 TB/s this way); plain loads keep the
// ~67 MB of L3 read hits.

typedef float f32x4 __attribute__((ext_vector_type(4)));

__global__ __launch_bounds__(256) void if_fwd_kernel(
    const f32x4* __restrict__ x,
    const float* __restrict__ thresh_p,
    f32x4* __restrict__ out,
    int n4)   // f32x4 positions per timestep
{
    const float th = thresh_p[0];
    const float m0 = 0.5f * th;

    // Block owns 1024 consecutive f32x4 per timestep; thread handles
    // base + 256*k, k=0..3 (wave-coalesced, block-contiguous).
    const int base = blockIdx.x * 1024 + threadIdx.x;

    // 16 independent 16B loads. Issue order t-major, so the t=0 compute below
    // only waits on the first 4 (s_waitcnt vmcnt(12)) while 12 stay in flight.
    f32x4 v[4][4];
#pragma unroll
    for (int t = 0; t < 4; ++t) {
#pragma unroll
        for (int k = 0; k < 4; ++k) {
            v[t][k] = x[t * n4 + base + 256 * k];
        }
    }

    // Hard scheduling fence: nothing crosses. All 16 loads are issued before
    // any dependent compute — this is what R4/R5 failed to get.
    __builtin_amdgcn_sched_barrier(0);

    f32x4 m[4];
#pragma unroll
    for (int k = 0; k < 4; ++k) m[k] = m0;

#pragma unroll
    for (int t = 0; t < 4; ++t) {
#pragma unroll
        for (int k = 0; k < 4; ++k) {
            m[k] += v[t][k];
            f32x4 s;
            s.x = (m[k].x >= th) ? th : 0.0f;
            s.y = (m[k].y >= th) ? th : 0.0f;
            s.z = (m[k].z >= th) ? th : 0.0f;
            s.w = (m[k].w >= th) ? th : 0.0f;
            out[t * n4 + base + 256 * k] = s;   // plain store, through L2
            m[k] -= s;
        }
    }
}

extern "C" void kernel_launch(void* const* d_in, const int* in_sizes, int n_in,
                              void* d_out, int out_size, void* d_ws, size_t ws_size,
                              hipStream_t stream) {
    const float* x      = (const float*)d_in[0];
    const float* thresh = (const float*)d_in[1];
    float* out          = (float*)d_out;

    const int total   = in_sizes[0];   // 33,554,432 = T*B*C*H*W (T=4)
    const int n_per_t = total / 4;     // 8,388,608
    const int n4      = n_per_t / 4;   // 2,097,152 f32x4 per timestep

    const int block = 256;
    const int grid  = n4 / (block * 4);   // 2048 blocks, exact

    if_fwd_kernel<<<grid, block, 0, stream>>>(
        (const f32x4*)x, thresh, (f32x4*)out, n4);
}